// Round 12
// baseline (303.037 us; speedup 1.0000x reference)
//
#include <hip/hip_runtime.h>

// ---------------------------------------------------------------------------
// 3-layer GraphSAGE (mean aggregation) + final linear.
// N=50000, 128 ch hidden, 800000 edges, out 16.
// R4: split-bf16 (hi/lo) MFMA GEMMs, K=256 combined; CSR de-atomic'd fill.
// R5/R6/R8 (REGRESSED). R7: agg unroll-8. R10: GEMM dbuf (269.8us best).
// R11: wide-gather agg = flat -> agg is L2-capacity bound, not MLP-bound.
// R12: XCD-pinned channel-sliced aggregate: block b -> slice b&3 (64B line),
//      round-robin dispatch pins slice s to XCDs {s,s+4} -> per-XCD feature
//      working set 3.2MB < 4MB L2. A/B: layers 1+3 sliced, layer 2 classic.
// ---------------------------------------------------------------------------

typedef short bf16x8 __attribute__((ext_vector_type(8)));  // 8 bf16 (4 VGPRs)
typedef float f32x4 __attribute__((ext_vector_type(4)));

__device__ __forceinline__ float bf16_to_f32(unsigned int lo16) {
  unsigned int u = lo16 << 16;
  return __builtin_bit_cast(float, u);
}
__device__ __forceinline__ unsigned short f32_to_bf16(float f) {
  unsigned int u = __builtin_bit_cast(unsigned int, f);
  unsigned int r = (u + 0x7FFFu + ((u >> 16) & 1u)) >> 16;  // RNE
  return (unsigned short)r;
}

// async global->LDS, 16B per lane; lds base must be wave-uniform.
__device__ __forceinline__ void gload_lds16(const void* g, void* lds_base) {
  __builtin_amdgcn_global_load_lds(
      (__attribute__((address_space(1))) unsigned int*)(uintptr_t)g,
      (__attribute__((address_space(3))) unsigned int*)(unsigned int)(uintptr_t)lds_base,
      16, 0, 0);
}

__global__ void k_zero_i32(int* __restrict__ p, int n) {
  int i = blockIdx.x * blockDim.x + threadIdx.x;
  if (i < n) p[i] = 0;
}

// fp32 -> bf16 hi/lo split, 4 elems/thread
__global__ __launch_bounds__(256) void k_split(const float* __restrict__ in,
                                               unsigned short* __restrict__ hi,
                                               unsigned short* __restrict__ lo, int n4) {
  int i = blockIdx.x * blockDim.x + threadIdx.x;
  if (i < n4) {
    float4 v = *reinterpret_cast<const float4*>(&in[(size_t)i * 4]);
    ushort4 h, l;
    h.x = f32_to_bf16(v.x); l.x = f32_to_bf16(v.x - bf16_to_f32(h.x));
    h.y = f32_to_bf16(v.y); l.y = f32_to_bf16(v.y - bf16_to_f32(h.y));
    h.z = f32_to_bf16(v.z); l.z = f32_to_bf16(v.z - bf16_to_f32(h.z));
    h.w = f32_to_bf16(v.w); l.w = f32_to_bf16(v.w - bf16_to_f32(h.w));
    *reinterpret_cast<ushort4*>(&hi[(size_t)i * 4]) = h;
    *reinterpret_cast<ushort4*>(&lo[(size_t)i * 4]) = l;
  }
}

// Weights: Wt[n][k] = (k<128 ? Wl[k][n] : Wr[k-128][n]), split hi/lo.
__global__ __launch_bounds__(256) void k_prep_w(const float* __restrict__ Wl,
                                                const float* __restrict__ Wr,
                                                unsigned short* __restrict__ Whi,
                                                unsigned short* __restrict__ Wlo) {
  int n = blockIdx.x, k = threadIdx.x;  // 128 blocks x 256 threads
  float v = (k < 128) ? Wl[(size_t)k * 128 + n] : Wr[(size_t)(k - 128) * 128 + n];
  unsigned short h = f32_to_bf16(v);
  Whi[(size_t)n * 256 + k] = h;
  Wlo[(size_t)n * 256 + k] = f32_to_bf16(v - bf16_to_f32(h));
}

// int32-vs-int64 edge_index detection
__global__ void k_detect(const int* __restrict__ ei, int* __restrict__ flag) {
  int t = threadIdx.x;
  int any = 0;
  for (int i = t; i < 1024; i += 256)
    if (ei[2 * i + 1] != 0) any = 1;
  if (any) atomicOr(flag, 1);
}

__device__ __forceinline__ int load_src(const int* ei, int E, int i, int is32) {
  return is32 ? ei[i] : ei[2 * i];
}
__device__ __forceinline__ int load_dst(const int* ei, int E, int i, int is32) {
  return is32 ? ei[E + i] : ei[2 * E + 2 * i];
}

// count degree + capture per-edge rank (removes atomic from k_fill)
__global__ __launch_bounds__(256) void k_count(const int* __restrict__ ei,
                                               const int* __restrict__ flag,
                                               int* __restrict__ deg,
                                               int* __restrict__ erank, int E) {
  int i = blockIdx.x * blockDim.x + threadIdx.x;
  if (i < E) {
    int is32 = *flag;
    erank[i] = atomicAdd(&deg[load_dst(ei, E, i, is32)], 1);
  }
}

// --- device-wide exclusive scan over deg (3 passes, 1024 elems/block) ------
__global__ __launch_bounds__(256) void k_scan1(const int* __restrict__ deg,
                                               int* __restrict__ bsum, int N) {
  __shared__ int s[256];
  int t = threadIdx.x;
  int base = blockIdx.x * 1024 + t * 4;
  int v = 0;
#pragma unroll
  for (int j = 0; j < 4; ++j) {
    int i = base + j;
    v += (i < N) ? deg[i] : 0;
  }
  s[t] = v;
  __syncthreads();
  for (int off = 128; off > 0; off >>= 1) {
    if (t < off) s[t] += s[t + off];
    __syncthreads();
  }
  if (t == 0) bsum[blockIdx.x] = s[0];
}

__global__ __launch_bounds__(1024) void k_scan2(int* __restrict__ bsum,
                                                int* __restrict__ row_ptr,
                                                int nb, int N) {
  __shared__ int s[1024];
  int t = threadIdx.x;
  int v = (t < nb) ? bsum[t] : 0;
  s[t] = v;
  __syncthreads();
  for (int off = 1; off < 1024; off <<= 1) {
    int add = (t >= off) ? s[t - off] : 0;
    __syncthreads();
    s[t] += add;
    __syncthreads();
  }
  if (t < nb) bsum[t] = s[t] - v;  // exclusive
  if (t == 1023) row_ptr[N] = s[1023];
}

__global__ __launch_bounds__(256) void k_scan3(const int* __restrict__ deg,
                                               const int* __restrict__ bsum,
                                               int* __restrict__ row_ptr,
                                               float* __restrict__ inv_deg, int N) {
  __shared__ int s[256];
  int t = threadIdx.x;
  int base = blockIdx.x * 1024 + t * 4;
  int v[4];
  int sum = 0;
#pragma unroll
  for (int j = 0; j < 4; ++j) {
    int i = base + j;
    v[j] = (i < N) ? deg[i] : 0;
    sum += v[j];
  }
  s[t] = sum;
  __syncthreads();
  for (int off = 1; off < 256; off <<= 1) {
    int add = (t >= off) ? s[t - off] : 0;
    __syncthreads();
    s[t] += add;
    __syncthreads();
  }
  int excl = s[t] - sum + bsum[blockIdx.x];
#pragma unroll
  for (int j = 0; j < 4; ++j) {
    int i = base + j;
    if (i < N) {
      row_ptr[i] = excl;
      inv_deg[i] = 1.0f / (float)((v[j] > 1) ? v[j] : 1);
      excl += v[j];
    }
  }
}

// pure scatter fill (rank precomputed)
__global__ __launch_bounds__(256) void k_fill(const int* __restrict__ ei,
                                              const int* __restrict__ flag,
                                              const int* __restrict__ row_ptr,
                                              const int* __restrict__ erank,
                                              int* __restrict__ col_idx, int E) {
  int i = blockIdx.x * blockDim.x + threadIdx.x;
  if (i < E) {
    int is32 = *flag;
    int d = load_dst(ei, E, i, is32);
    int s = load_src(ei, E, i, is32);
    col_idx[row_ptr[d] + erank[i]] = s;
  }
}

// Classic (R7) aggregate: one wave per node, 4B/lane, unroll-8. A/B anchor.
__global__ __launch_bounds__(256) void k_aggregate(const unsigned short* __restrict__ Xhi,
                                                   const int* __restrict__ row_ptr,
                                                   const int* __restrict__ col_idx,
                                                   const float* __restrict__ inv_deg,
                                                   unsigned int* __restrict__ Mhi,
                                                   unsigned int* __restrict__ Mlo, int N) {
  int gw = (int)((blockIdx.x * blockDim.x + threadIdx.x) >> 6);
  int lane = threadIdx.x & 63;
  if (gw >= N) return;
  int s = row_ptr[gw], e = row_ptr[gw + 1];
  const unsigned int* Xp =
      reinterpret_cast<const unsigned int*>(Xhi) + lane;  // row stride 64 u32
  float ax[8], ay[8];
#pragma unroll
  for (int q = 0; q < 8; ++q) { ax[q] = 0.f; ay[q] = 0.f; }
  int j = s;
  for (; j + 8 <= e; j += 8) {
    unsigned int v[8];
#pragma unroll
    for (int q = 0; q < 8; ++q) v[q] = Xp[(size_t)col_idx[j + q] * 64];
#pragma unroll
    for (int q = 0; q < 8; ++q) {
      ax[q] += bf16_to_f32(v[q] & 0xFFFFu);
      ay[q] += bf16_to_f32(v[q] >> 16);
    }
  }
  for (; j + 4 <= e; j += 4) {
    unsigned int v[4];
#pragma unroll
    for (int q = 0; q < 4; ++q) v[q] = Xp[(size_t)col_idx[j + q] * 64];
#pragma unroll
    for (int q = 0; q < 4; ++q) {
      ax[q] += bf16_to_f32(v[q] & 0xFFFFu);
      ay[q] += bf16_to_f32(v[q] >> 16);
    }
  }
  for (; j < e; ++j) {
    unsigned int v = Xp[(size_t)col_idx[j] * 64];
    ax[0] += bf16_to_f32(v & 0xFFFFu);
    ay[0] += bf16_to_f32(v >> 16);
  }
  float inv = inv_deg[gw];
  float rx = ((ax[0] + ax[1]) + (ax[2] + ax[3])) + ((ax[4] + ax[5]) + (ax[6] + ax[7]));
  float ry = ((ay[0] + ay[1]) + (ay[2] + ay[3])) + ((ay[4] + ay[5]) + (ay[6] + ay[7]));
  rx *= inv;
  ry *= inv;
  unsigned int hx = f32_to_bf16(rx), hy = f32_to_bf16(ry);
  unsigned int lx = f32_to_bf16(rx - bf16_to_f32(hx));
  unsigned int ly = f32_to_bf16(ry - bf16_to_f32(hy));
  Mhi[(size_t)gw * 64 + lane] = hx | (hy << 16);
  Mlo[(size_t)gw * 64 + lane] = lx | (ly << 16);
}

// XCD-pinned sliced aggregate: block b -> channel slice (b&3)*32ch (64B line),
// node chunk b>>2 (16 nodes: 4 waves x 4 16-lane groups). Round-robin
// blockIdx->XCD pins slice s to XCDs {s, s+4}: per-XCD feature working set
// = N*64B = 3.2MB < 4MB L2. Each lane owns 2 channels -> no cross-lane
// reduce; M layout identical to classic.
__global__ __launch_bounds__(256) void k_agg_xcd(const unsigned short* __restrict__ Xhi,
                                                 const int* __restrict__ row_ptr,
                                                 const int* __restrict__ col_idx,
                                                 const float* __restrict__ inv_deg,
                                                 unsigned int* __restrict__ Mhi,
                                                 unsigned int* __restrict__ Mlo, int N) {
  int b = blockIdx.x;
  int slice = b & 3;   // 16 u32 = 32 channels = 64B
  int chunk = b >> 2;  // 16 nodes per chunk
  int t = threadIdx.x;
  int wave = t >> 6, lane = t & 63;
  int grp = lane >> 4, sl = lane & 15;
  int node = chunk * 16 + wave * 4 + grp;
  if (node >= N) return;
  int s = row_ptr[node], e = row_ptr[node + 1];
  const unsigned int* Xp =
      reinterpret_cast<const unsigned int*>(Xhi) + slice * 16 + sl;  // row stride 64 u32
  float ax0 = 0.f, ay0 = 0.f, ax1 = 0.f, ay1 = 0.f;
  float ax2 = 0.f, ay2 = 0.f, ax3 = 0.f, ay3 = 0.f;
  int j = s;
  for (; j + 4 <= e; j += 4) {
    unsigned int v0 = Xp[(size_t)col_idx[j] * 64];
    unsigned int v1 = Xp[(size_t)col_idx[j + 1] * 64];
    unsigned int v2 = Xp[(size_t)col_idx[j + 2] * 64];
    unsigned int v3 = Xp[(size_t)col_idx[j + 3] * 64];
    ax0 += bf16_to_f32(v0 & 0xFFFFu); ay0 += bf16_to_f32(v0 >> 16);
    ax1 += bf16_to_f32(v1 & 0xFFFFu); ay1 += bf16_to_f32(v1 >> 16);
    ax2 += bf16_to_f32(v2 & 0xFFFFu); ay2 += bf16_to_f32(v2 >> 16);
    ax3 += bf16_to_f32(v3 & 0xFFFFu); ay3 += bf16_to_f32(v3 >> 16);
  }
  for (; j < e; ++j) {
    unsigned int v = Xp[(size_t)col_idx[j] * 64];
    ax0 += bf16_to_f32(v & 0xFFFFu);
    ay0 += bf16_to_f32(v >> 16);
  }
  float inv = inv_deg[node];
  float rx = ((ax0 + ax1) + (ax2 + ax3)) * inv;
  float ry = ((ay0 + ay1) + (ay2 + ay3)) * inv;
  unsigned int hx = f32_to_bf16(rx), hy = f32_to_bf16(ry);
  unsigned int lx = f32_to_bf16(rx - bf16_to_f32(hx));
  unsigned int ly = f32_to_bf16(ry - bf16_to_f32(hy));
  Mhi[(size_t)node * 64 + slice * 16 + sl] = hx | (hy << 16);
  Mlo[(size_t)node * 64 + slice * 16 + sl] = lx | (ly << 16);
}

// MFMA GEMM: Out = relu([A1 | A2](N x 256) @ Wt^T + bias), split-bf16 3-pass.
// Block: 128 rows x 128 cols, 4 waves (2x2), wave = 64x64 via 4x4 16x16x32.
// Double-buffered kt-loop (R10).
__global__ __launch_bounds__(256) void k_mfma_gemm(
    const unsigned short* __restrict__ A1hi, const unsigned short* __restrict__ A1lo,
    const unsigned short* __restrict__ A2hi, const unsigned short* __restrict__ A2lo,
    const unsigned short* __restrict__ Whi, const unsigned short* __restrict__ Wlo,
    const float* __restrict__ bias,
    unsigned short* __restrict__ Ohi, unsigned short* __restrict__ Olo, int N) {
  __shared__ unsigned short sAhi[2][128 * 32], sAlo[2][128 * 32];
  __shared__ unsigned short sBhi[2][128 * 32], sBlo[2][128 * 32];
  int t = threadIdx.x;
  int lane = t & 63;
  int w = t >> 6;
  int wr = (w >> 1) * 64, wc = (w & 1) * 64;
  int block_row = blockIdx.x * 128;

  f32x4 acc[4][4];
#pragma unroll
  for (int m = 0; m < 4; ++m)
#pragma unroll
    for (int n = 0; n < 4; ++n) acc[m][n] = f32x4{0.f, 0.f, 0.f, 0.f};

  int kg = lane & 3;           // 16B group within 64B row
  int rr = lane >> 2;          // 0..15 row-within-chunk
  int fr = lane & 15;          // fragment row/col
  int fkb = (lane >> 4) * 16;  // fragment k byte offset

  auto stage = [&](int kt, int b) {
    const unsigned short* gsrc;
    unsigned short* lbase;
    int isA = (w < 2);
    if (w == 0) { gsrc = (kt < 4) ? A1hi : A2hi; lbase = sAhi[b]; }
    else if (w == 1) { gsrc = (kt < 4) ? A1lo : A2lo; lbase = sAlo[b]; }
    else if (w == 2) { gsrc = Whi; lbase = sBhi[b]; }
    else { gsrc = Wlo; lbase = sBlo[b]; }
#pragma unroll
    for (int c = 0; c < 8; ++c) {
      int idx = c * 16 + rr;  // A: row; B: col
      const char* src;
      if (isA) {
        int rg = block_row + idx;
        if (rg > N - 1) rg = N - 1;
        src = (const char*)gsrc + (size_t)rg * 256 + (kt & 3) * 64 + kg * 16;
      } else {
        src = (const char*)gsrc + (size_t)idx * 512 + kt * 64 + kg * 16;
      }
      gload_lds16(src, (char*)lbase + c * 1024);
    }
  };

  stage(0, 0);
  __syncthreads();

  for (int kt = 0; kt < 8; ++kt) {
    int cur = kt & 1;
    if (kt < 7) stage(kt + 1, cur ^ 1);
    bf16x8 a_hi[4], a_lo[4], b_hi[4], b_lo[4];
#pragma unroll
    for (int m = 0; m < 4; ++m) {
      int row = wr + m * 16 + fr;
      a_hi[m] = *reinterpret_cast<const bf16x8*>((const char*)sAhi[cur] + row * 64 + fkb);
      a_lo[m] = *reinterpret_cast<const bf16x8*>((const char*)sAlo[cur] + row * 64 + fkb);
    }
#pragma unroll
    for (int n = 0; n < 4; ++n) {
      int col = wc + n * 16 + fr;
      b_hi[n] = *reinterpret_cast<const bf16x8*>((const char*)sBhi[cur] + col * 64 + fkb);
      b_lo[n] = *reinterpret_cast<const bf16x8*>((const char*)sBlo[cur] + col * 64 + fkb);
    }
#pragma unroll
    for (int m = 0; m < 4; ++m)
#pragma unroll
      for (int n = 0; n < 4; ++n) {
        acc[m][n] = __builtin_amdgcn_mfma_f32_16x16x32_bf16(a_hi[m], b_hi[n], acc[m][n], 0, 0, 0);
        acc[m][n] = __builtin_amdgcn_mfma_f32_16x16x32_bf16(a_hi[m], b_lo[n], acc[m][n], 0, 0, 0);
        acc[m][n] = __builtin_amdgcn_mfma_f32_16x16x32_bf16(a_lo[m], b_hi[n], acc[m][n], 0, 0, 0);
      }
    __syncthreads();
  }

  float bv[4];
#pragma unroll
  for (int n = 0; n < 4; ++n) bv[n] = bias[wc + n * 16 + (lane & 15)];
#pragma unroll
  for (int m = 0; m < 4; ++m) {
#pragma unroll
    for (int n = 0; n < 4; ++n) {
#pragma unroll
      for (int j = 0; j < 4; ++j) {
        int row_l = wr + m * 16 + (lane >> 4) * 4 + j;
        int g = block_row + row_l;
        if (g < N) {
          int col = wc + n * 16 + (lane & 15);
          float v = fmaxf(acc[m][n][j] + bv[n], 0.f);
          unsigned short h = f32_to_bf16(v);
          Ohi[(size_t)g * 128 + col] = h;
          Olo[(size_t)g * 128 + col] = f32_to_bf16(v - bf16_to_f32(h));
        }
      }
    }
  }
}

// Final: Out[N][16] = H[N][128] @ W[128][16] + b; H reconstructed from hi+lo.
__global__ __launch_bounds__(256) void k_final(const unsigned short* __restrict__ Hhi,
                                               const unsigned short* __restrict__ Hlo,
                                               const float* __restrict__ W,
                                               const float* __restrict__ b,
                                               float* __restrict__ Out, int N) {
  __shared__ float sH[16][128];
  __shared__ float sW[128][16];
  __shared__ float sb[16];
  int t = threadIdx.x;
  int node0 = blockIdx.x * 16;
  {
    int row = t >> 4, q = t & 15;  // 8 elems each
    int g = node0 + row;
    if (g < N) {
      uint4 hv = *reinterpret_cast<const uint4*>(&Hhi[(size_t)g * 128 + q * 8]);
      uint4 lv = *reinterpret_cast<const uint4*>(&Hlo[(size_t)g * 128 + q * 8]);
      const unsigned short* hp = (const unsigned short*)&hv;
      const unsigned short* lp = (const unsigned short*)&lv;
#pragma unroll
      for (int e = 0; e < 8; ++e)
        sH[row][q * 8 + e] = bf16_to_f32(hp[e]) + bf16_to_f32(lp[e]);
    } else {
#pragma unroll
      for (int e = 0; e < 8; ++e) sH[row][q * 8 + e] = 0.f;
    }
  }
  for (int j = t; j < 512; j += 256) {
    int row = j >> 2, q = j & 3;
    *reinterpret_cast<float4*>(&sW[row][q * 4]) =
        *reinterpret_cast<const float4*>(&W[(size_t)row * 16 + q * 4]);
  }
  if (t < 16) sb[t] = b[t];
  __syncthreads();
  int node = t >> 4, col = t & 15;
  float acc = sb[col];
#pragma unroll 8
  for (int k = 0; k < 128; ++k) acc = fmaf(sH[node][k], sW[k][col], acc);
  int g = node0 + node;
  if (g < N) Out[(size_t)g * 16 + col] = acc;
}

extern "C" void kernel_launch(void* const* d_in, const int* in_sizes, int n_in,
                              void* d_out, int out_size, void* d_ws, size_t ws_size,
                              hipStream_t stream) {
  if (n_in < 13) return;
  const float* x = (const float*)d_in[0];
  const int* ei = (const int*)d_in[1];
  const float* W1l = (const float*)d_in[2];
  const float* b1 = (const float*)d_in[3];
  const float* W1r = (const float*)d_in[4];
  const float* W2l = (const float*)d_in[5];
  const float* b2 = (const float*)d_in[6];
  const float* W2r = (const float*)d_in[7];
  const float* W3l = (const float*)d_in[8];
  const float* b3 = (const float*)d_in[9];
  const float* W3r = (const float*)d_in[10];
  const float* Wlin = (const float*)d_in[11];
  const float* blin = (const float*)d_in[12];
  float* out = (float*)d_out;

  const int N = in_sizes[0] / 128;
  const int E = in_sizes[1] / 2;

  char* w = (char*)d_ws;
  size_t off = 0;
  auto alloc = [&](size_t bytes) -> void* {
    off = (off + 255) & ~(size_t)255;
    void* p = (void*)(w + off);
    off += bytes;
    return p;
  };
  size_t actB = (size_t)N * 128 * 2;
  unsigned short* Xhi = (unsigned short*)alloc(actB);
  unsigned short* Xlo = (unsigned short*)alloc(actB);
  unsigned short* Ahi = (unsigned short*)alloc(actB);
  unsigned short* Alo = (unsigned short*)alloc(actB);
  unsigned short* Mhi = (unsigned short*)alloc(actB);
  unsigned short* Mlo = (unsigned short*)alloc(actB);
  unsigned short* Wt[6];
  for (int i = 0; i < 6; ++i) Wt[i] = (unsigned short*)alloc(128 * 256 * 2);
  int* deg = (int*)alloc((size_t)N * 4);
  int* row_ptr = (int*)alloc((size_t)(N + 1) * 4);
  int* col_idx = (int*)alloc((size_t)E * 4);
  int* erank = (int*)alloc((size_t)E * 4);
  float* invdeg = (float*)alloc((size_t)N * 4);
  int* flag = (int*)alloc(4);
  int* bsum = (int*)alloc((size_t)1024 * 4);
  (void)ws_size;

  const int nbScan = (N + 1023) / 1024;

  // CSR build + operand prep
  k_zero_i32<<<(N + 255) / 256, 256, 0, stream>>>(deg, N);
  k_zero_i32<<<1, 256, 0, stream>>>(flag, 1);
  k_detect<<<1, 256, 0, stream>>>(ei, flag);
  k_count<<<(E + 255) / 256, 256, 0, stream>>>(ei, flag, deg, erank, E);
  k_split<<<(N * 32 + 255) / 256, 256, 0, stream>>>(x, Xhi, Xlo, N * 32);
  k_prep_w<<<128, 256, 0, stream>>>(W1l, W1r, Wt[0], Wt[1]);
  k_prep_w<<<128, 256, 0, stream>>>(W2l, W2r, Wt[2], Wt[3]);
  k_prep_w<<<128, 256, 0, stream>>>(W3l, W3r, Wt[4], Wt[5]);
  k_scan1<<<nbScan, 256, 0, stream>>>(deg, bsum, N);
  k_scan2<<<1, 1024, 0, stream>>>(bsum, row_ptr, nbScan, N);
  k_scan3<<<nbScan, 256, 0, stream>>>(deg, bsum, row_ptr, invdeg, N);
  k_fill<<<(E + 255) / 256, 256, 0, stream>>>(ei, flag, row_ptr, erank, col_idx, E);

  int aggBlocks = (N * 64 + 255) / 256;
  int sliceBlocks = ((N + 15) / 16) * 4;
  int gemmBlocks = (N + 127) / 128;

  // layer 1: X -> A (h1)  [XCD-pinned sliced]
  k_agg_xcd<<<sliceBlocks, 256, 0, stream>>>(Xhi, row_ptr, col_idx, invdeg,
                                             (unsigned int*)Mhi, (unsigned int*)Mlo, N);
  k_mfma_gemm<<<gemmBlocks, 256, 0, stream>>>(Mhi, Mlo, Xhi, Xlo, Wt[0], Wt[1], b1,
                                              Ahi, Alo, N);
  // layer 2: A -> X (h2)  [classic anchor]
  k_aggregate<<<aggBlocks, 256, 0, stream>>>(Ahi, row_ptr, col_idx, invdeg,
                                             (unsigned int*)Mhi, (unsigned int*)Mlo, N);
  k_mfma_gemm<<<gemmBlocks, 256, 0, stream>>>(Mhi, Mlo, Ahi, Alo, Wt[2], Wt[3], b2,
                                              Xhi, Xlo, N);
  // layer 3: X -> A (h3)  [XCD-pinned sliced]
  k_agg_xcd<<<sliceBlocks, 256, 0, stream>>>(Xhi, row_ptr, col_idx, invdeg,
                                             (unsigned int*)Mhi, (unsigned int*)Mlo, N);
  k_mfma_gemm<<<gemmBlocks, 256, 0, stream>>>(Mhi, Mlo, Xhi, Xlo, Wt[4], Wt[5], b3,
                                              Ahi, Alo, N);
  // final linear
  k_final<<<(N + 15) / 16, 256, 0, stream>>>(Ahi, Alo, Wlin, blin, out, N);
}

// Round 13
// 244.997 us; speedup vs baseline: 1.2369x; 1.2369x over previous
//
#include <hip/hip_runtime.h>

// ---------------------------------------------------------------------------
// 3-layer GraphSAGE (mean aggregation) + final linear.
// N=50000, 128 ch hidden, 800000 edges, out 16.
// R4: split-bf16 (hi/lo) MFMA GEMMs, K=256 combined; CSR de-atomic'd fill.
// R5/R6/R8/R12 (REGRESSED, reverted). R7: agg unroll-8. R10: GEMM dbuf
// (269.8us best). R11 flat -> aggregate at memory-system ceiling
// (205MB logical / 33us = 6.2TB/s ~ achievable BW).
// R13: overhead reclaim on R10 base:
//   - 3x k_prep_w -> 1 launch; flag-zero folded into k_detect.
//   - layer-3 GEMM fused with final linear: h3 tile -> (dead) staging LDS ->
//     24 MFMA/wave h3@Wlin (split-bf16 3-pass) -> fp32 out. Kills k_final
//     launch + 25.6MB of h3 HBM write+read.
// ---------------------------------------------------------------------------

typedef short bf16x8 __attribute__((ext_vector_type(8)));  // 8 bf16 (4 VGPRs)
typedef float f32x4 __attribute__((ext_vector_type(4)));

__device__ __forceinline__ float bf16_to_f32(unsigned int lo16) {
  unsigned int u = lo16 << 16;
  return __builtin_bit_cast(float, u);
}
__device__ __forceinline__ unsigned short f32_to_bf16(float f) {
  unsigned int u = __builtin_bit_cast(unsigned int, f);
  unsigned int r = (u + 0x7FFFu + ((u >> 16) & 1u)) >> 16;  // RNE
  return (unsigned short)r;
}

// async global->LDS, 16B per lane; lds base must be wave-uniform.
__device__ __forceinline__ void gload_lds16(const void* g, void* lds_base) {
  __builtin_amdgcn_global_load_lds(
      (__attribute__((address_space(1))) unsigned int*)(uintptr_t)g,
      (__attribute__((address_space(3))) unsigned int*)(unsigned int)(uintptr_t)lds_base,
      16, 0, 0);
}

__global__ void k_zero_i32(int* __restrict__ p, int n) {
  int i = blockIdx.x * blockDim.x + threadIdx.x;
  if (i < n) p[i] = 0;
}

// fp32 -> bf16 hi/lo split, 4 elems/thread
__global__ __launch_bounds__(256) void k_split(const float* __restrict__ in,
                                               unsigned short* __restrict__ hi,
                                               unsigned short* __restrict__ lo, int n4) {
  int i = blockIdx.x * blockDim.x + threadIdx.x;
  if (i < n4) {
    float4 v = *reinterpret_cast<const float4*>(&in[(size_t)i * 4]);
    ushort4 h, l;
    h.x = f32_to_bf16(v.x); l.x = f32_to_bf16(v.x - bf16_to_f32(h.x));
    h.y = f32_to_bf16(v.y); l.y = f32_to_bf16(v.y - bf16_to_f32(h.y));
    h.z = f32_to_bf16(v.z); l.z = f32_to_bf16(v.z - bf16_to_f32(h.z));
    h.w = f32_to_bf16(v.w); l.w = f32_to_bf16(v.w - bf16_to_f32(h.w));
    *reinterpret_cast<ushort4*>(&hi[(size_t)i * 4]) = h;
    *reinterpret_cast<ushort4*>(&lo[(size_t)i * 4]) = l;
  }
}

// All 3 layers' weights in one launch: 384 blocks; layer = b>>7, n = b&127.
// Wt[n][k] = (k<128 ? Wl[k][n] : Wr[k-128][n]), split hi/lo.
__global__ __launch_bounds__(256) void k_prep_w3(
    const float* __restrict__ W1l, const float* __restrict__ W1r,
    const float* __restrict__ W2l, const float* __restrict__ W2r,
    const float* __restrict__ W3l, const float* __restrict__ W3r,
    unsigned short* __restrict__ Whi1, unsigned short* __restrict__ Wlo1,
    unsigned short* __restrict__ Whi2, unsigned short* __restrict__ Wlo2,
    unsigned short* __restrict__ Whi3, unsigned short* __restrict__ Wlo3) {
  int layer = blockIdx.x >> 7;
  int n = blockIdx.x & 127;
  int k = threadIdx.x;
  const float* Wl = (layer == 0) ? W1l : (layer == 1) ? W2l : W3l;
  const float* Wr = (layer == 0) ? W1r : (layer == 1) ? W2r : W3r;
  unsigned short* Whi = (layer == 0) ? Whi1 : (layer == 1) ? Whi2 : Whi3;
  unsigned short* Wlo = (layer == 0) ? Wlo1 : (layer == 1) ? Wlo2 : Wlo3;
  float v = (k < 128) ? Wl[(size_t)k * 128 + n] : Wr[(size_t)(k - 128) * 128 + n];
  unsigned short h = f32_to_bf16(v);
  Whi[(size_t)n * 256 + k] = h;
  Wlo[(size_t)n * 256 + k] = f32_to_bf16(v - bf16_to_f32(h));
}

// int32-vs-int64 edge_index detection; zeroes flag itself (single block).
__global__ void k_detect(const int* __restrict__ ei, int* __restrict__ flag) {
  int t = threadIdx.x;
  if (t == 0) *flag = 0;
  __syncthreads();
  int any = 0;
  for (int i = t; i < 1024; i += 256)
    if (ei[2 * i + 1] != 0) any = 1;
  if (any) atomicOr(flag, 1);
}

__device__ __forceinline__ int load_src(const int* ei, int E, int i, int is32) {
  return is32 ? ei[i] : ei[2 * i];
}
__device__ __forceinline__ int load_dst(const int* ei, int E, int i, int is32) {
  return is32 ? ei[E + i] : ei[2 * E + 2 * i];
}

// count degree + capture per-edge rank (removes atomic from k_fill)
__global__ __launch_bounds__(256) void k_count(const int* __restrict__ ei,
                                               const int* __restrict__ flag,
                                               int* __restrict__ deg,
                                               int* __restrict__ erank, int E) {
  int i = blockIdx.x * blockDim.x + threadIdx.x;
  if (i < E) {
    int is32 = *flag;
    erank[i] = atomicAdd(&deg[load_dst(ei, E, i, is32)], 1);
  }
}

// --- device-wide exclusive scan over deg (3 passes, 1024 elems/block) ------
__global__ __launch_bounds__(256) void k_scan1(const int* __restrict__ deg,
                                               int* __restrict__ bsum, int N) {
  __shared__ int s[256];
  int t = threadIdx.x;
  int base = blockIdx.x * 1024 + t * 4;
  int v = 0;
#pragma unroll
  for (int j = 0; j < 4; ++j) {
    int i = base + j;
    v += (i < N) ? deg[i] : 0;
  }
  s[t] = v;
  __syncthreads();
  for (int off = 128; off > 0; off >>= 1) {
    if (t < off) s[t] += s[t + off];
    __syncthreads();
  }
  if (t == 0) bsum[blockIdx.x] = s[0];
}

__global__ __launch_bounds__(1024) void k_scan2(int* __restrict__ bsum,
                                                int* __restrict__ row_ptr,
                                                int nb, int N) {
  __shared__ int s[1024];
  int t = threadIdx.x;
  int v = (t < nb) ? bsum[t] : 0;
  s[t] = v;
  __syncthreads();
  for (int off = 1; off < 1024; off <<= 1) {
    int add = (t >= off) ? s[t - off] : 0;
    __syncthreads();
    s[t] += add;
    __syncthreads();
  }
  if (t < nb) bsum[t] = s[t] - v;  // exclusive
  if (t == 1023) row_ptr[N] = s[1023];
}

__global__ __launch_bounds__(256) void k_scan3(const int* __restrict__ deg,
                                               const int* __restrict__ bsum,
                                               int* __restrict__ row_ptr,
                                               float* __restrict__ inv_deg, int N) {
  __shared__ int s[256];
  int t = threadIdx.x;
  int base = blockIdx.x * 1024 + t * 4;
  int v[4];
  int sum = 0;
#pragma unroll
  for (int j = 0; j < 4; ++j) {
    int i = base + j;
    v[j] = (i < N) ? deg[i] : 0;
    sum += v[j];
  }
  s[t] = sum;
  __syncthreads();
  for (int off = 1; off < 256; off <<= 1) {
    int add = (t >= off) ? s[t - off] : 0;
    __syncthreads();
    s[t] += add;
    __syncthreads();
  }
  int excl = s[t] - sum + bsum[blockIdx.x];
#pragma unroll
  for (int j = 0; j < 4; ++j) {
    int i = base + j;
    if (i < N) {
      row_ptr[i] = excl;
      inv_deg[i] = 1.0f / (float)((v[j] > 1) ? v[j] : 1);
      excl += v[j];
    }
  }
}

// pure scatter fill (rank precomputed)
__global__ __launch_bounds__(256) void k_fill(const int* __restrict__ ei,
                                              const int* __restrict__ flag,
                                              const int* __restrict__ row_ptr,
                                              const int* __restrict__ erank,
                                              int* __restrict__ col_idx, int E) {
  int i = blockIdx.x * blockDim.x + threadIdx.x;
  if (i < E) {
    int is32 = *flag;
    int d = load_dst(ei, E, i, is32);
    int s = load_src(ei, E, i, is32);
    col_idx[row_ptr[d] + erank[i]] = s;
  }
}

// One wave per node, 4B/lane = full 256B row per load, unroll-8 (8 gathers in
// flight), per-lane hi/lo packed stores. No shuffles, no LDS. (R7 body.)
__global__ __launch_bounds__(256) void k_aggregate(const unsigned short* __restrict__ Xhi,
                                                   const int* __restrict__ row_ptr,
                                                   const int* __restrict__ col_idx,
                                                   const float* __restrict__ inv_deg,
                                                   unsigned int* __restrict__ Mhi,
                                                   unsigned int* __restrict__ Mlo, int N) {
  int gw = (int)((blockIdx.x * blockDim.x + threadIdx.x) >> 6);
  int lane = threadIdx.x & 63;
  if (gw >= N) return;
  int s = row_ptr[gw], e = row_ptr[gw + 1];
  const unsigned int* Xp =
      reinterpret_cast<const unsigned int*>(Xhi) + lane;  // row stride 64 u32
  float ax[8], ay[8];
#pragma unroll
  for (int q = 0; q < 8; ++q) { ax[q] = 0.f; ay[q] = 0.f; }
  int j = s;
  for (; j + 8 <= e; j += 8) {
    unsigned int v[8];
#pragma unroll
    for (int q = 0; q < 8; ++q) v[q] = Xp[(size_t)col_idx[j + q] * 64];
#pragma unroll
    for (int q = 0; q < 8; ++q) {
      ax[q] += bf16_to_f32(v[q] & 0xFFFFu);
      ay[q] += bf16_to_f32(v[q] >> 16);
    }
  }
  for (; j + 4 <= e; j += 4) {
    unsigned int v[4];
#pragma unroll
    for (int q = 0; q < 4; ++q) v[q] = Xp[(size_t)col_idx[j + q] * 64];
#pragma unroll
    for (int q = 0; q < 4; ++q) {
      ax[q] += bf16_to_f32(v[q] & 0xFFFFu);
      ay[q] += bf16_to_f32(v[q] >> 16);
    }
  }
  for (; j < e; ++j) {
    unsigned int v = Xp[(size_t)col_idx[j] * 64];
    ax[0] += bf16_to_f32(v & 0xFFFFu);
    ay[0] += bf16_to_f32(v >> 16);
  }
  float inv = inv_deg[gw];
  float rx = ((ax[0] + ax[1]) + (ax[2] + ax[3])) + ((ax[4] + ax[5]) + (ax[6] + ax[7]));
  float ry = ((ay[0] + ay[1]) + (ay[2] + ay[3])) + ((ay[4] + ay[5]) + (ay[6] + ay[7]));
  rx *= inv;
  ry *= inv;
  unsigned int hx = f32_to_bf16(rx), hy = f32_to_bf16(ry);
  unsigned int lx = f32_to_bf16(rx - bf16_to_f32(hx));
  unsigned int ly = f32_to_bf16(ry - bf16_to_f32(hy));
  Mhi[(size_t)gw * 64 + lane] = hx | (hy << 16);
  Mlo[(size_t)gw * 64 + lane] = lx | (ly << 16);
}

// MFMA GEMM: Out = relu([A1 | A2](N x 256) @ Wt^T + bias), split-bf16 3-pass.
// Block: 128 rows x 128 cols, 4 waves (2x2), wave = 64x64 via 4x4 16x16x32.
// Double-buffered kt-loop (R10). Layers 1-2.
__global__ __launch_bounds__(256) void k_mfma_gemm(
    const unsigned short* __restrict__ A1hi, const unsigned short* __restrict__ A1lo,
    const unsigned short* __restrict__ A2hi, const unsigned short* __restrict__ A2lo,
    const unsigned short* __restrict__ Whi, const unsigned short* __restrict__ Wlo,
    const float* __restrict__ bias,
    unsigned short* __restrict__ Ohi, unsigned short* __restrict__ Olo, int N) {
  __shared__ unsigned short sAhi[2][128 * 32], sAlo[2][128 * 32];
  __shared__ unsigned short sBhi[2][128 * 32], sBlo[2][128 * 32];
  int t = threadIdx.x;
  int lane = t & 63;
  int w = t >> 6;
  int wr = (w >> 1) * 64, wc = (w & 1) * 64;
  int block_row = blockIdx.x * 128;

  f32x4 acc[4][4];
#pragma unroll
  for (int m = 0; m < 4; ++m)
#pragma unroll
    for (int n = 0; n < 4; ++n) acc[m][n] = f32x4{0.f, 0.f, 0.f, 0.f};

  int kg = lane & 3;
  int rr = lane >> 2;
  int fr = lane & 15;
  int fkb = (lane >> 4) * 16;

  auto stage = [&](int kt, int b) {
    const unsigned short* gsrc;
    unsigned short* lbase;
    int isA = (w < 2);
    if (w == 0) { gsrc = (kt < 4) ? A1hi : A2hi; lbase = sAhi[b]; }
    else if (w == 1) { gsrc = (kt < 4) ? A1lo : A2lo; lbase = sAlo[b]; }
    else if (w == 2) { gsrc = Whi; lbase = sBhi[b]; }
    else { gsrc = Wlo; lbase = sBlo[b]; }
#pragma unroll
    for (int c = 0; c < 8; ++c) {
      int idx = c * 16 + rr;
      const char* src;
      if (isA) {
        int rg = block_row + idx;
        if (rg > N - 1) rg = N - 1;
        src = (const char*)gsrc + (size_t)rg * 256 + (kt & 3) * 64 + kg * 16;
      } else {
        src = (const char*)gsrc + (size_t)idx * 512 + kt * 64 + kg * 16;
      }
      gload_lds16(src, (char*)lbase + c * 1024);
    }
  };

  stage(0, 0);
  __syncthreads();

  for (int kt = 0; kt < 8; ++kt) {
    int cur = kt & 1;
    if (kt < 7) stage(kt + 1, cur ^ 1);
    bf16x8 a_hi[4], a_lo[4], b_hi[4], b_lo[4];
#pragma unroll
    for (int m = 0; m < 4; ++m) {
      int row = wr + m * 16 + fr;
      a_hi[m] = *reinterpret_cast<const bf16x8*>((const char*)sAhi[cur] + row * 64 + fkb);
      a_lo[m] = *reinterpret_cast<const bf16x8*>((const char*)sAlo[cur] + row * 64 + fkb);
    }
#pragma unroll
    for (int n = 0; n < 4; ++n) {
      int col = wc + n * 16 + fr;
      b_hi[n] = *reinterpret_cast<const bf16x8*>((const char*)sBhi[cur] + col * 64 + fkb);
      b_lo[n] = *reinterpret_cast<const bf16x8*>((const char*)sBlo[cur] + col * 64 + fkb);
    }
#pragma unroll
    for (int m = 0; m < 4; ++m)
#pragma unroll
      for (int n = 0; n < 4; ++n) {
        acc[m][n] = __builtin_amdgcn_mfma_f32_16x16x32_bf16(a_hi[m], b_hi[n], acc[m][n], 0, 0, 0);
        acc[m][n] = __builtin_amdgcn_mfma_f32_16x16x32_bf16(a_hi[m], b_lo[n], acc[m][n], 0, 0, 0);
        acc[m][n] = __builtin_amdgcn_mfma_f32_16x16x32_bf16(a_lo[m], b_hi[n], acc[m][n], 0, 0, 0);
      }
    __syncthreads();
  }

  float bv[4];
#pragma unroll
  for (int n = 0; n < 4; ++n) bv[n] = bias[wc + n * 16 + (lane & 15)];
#pragma unroll
  for (int m = 0; m < 4; ++m) {
#pragma unroll
    for (int n = 0; n < 4; ++n) {
#pragma unroll
      for (int j = 0; j < 4; ++j) {
        int row_l = wr + m * 16 + (lane >> 4) * 4 + j;
        int g = block_row + row_l;
        if (g < N) {
          int col = wc + n * 16 + (lane & 15);
          float v = fmaxf(acc[m][n][j] + bv[n], 0.f);
          unsigned short h = f32_to_bf16(v);
          Ohi[(size_t)g * 128 + col] = h;
          Olo[(size_t)g * 128 + col] = f32_to_bf16(v - bf16_to_f32(h));
        }
      }
    }
  }
}

// Layer-3 GEMM with fused final linear: after the kt-loop, h3 (bias+relu) is
// written into the now-dead 64KB staging LDS as bf16 hi/lo, then each wave
// does 8 MFMA positions x 3 passes of h3 @ Wlin (+blin) -> fp32 out[N][16].
// Wlin fragments (split-bf16) preloaded per-lane at kernel start.
__global__ __launch_bounds__(256) void k_mfma_gemm_final(
    const unsigned short* __restrict__ A1hi, const unsigned short* __restrict__ A1lo,
    const unsigned short* __restrict__ A2hi, const unsigned short* __restrict__ A2lo,
    const unsigned short* __restrict__ Whi, const unsigned short* __restrict__ Wlo,
    const float* __restrict__ bias,
    const float* __restrict__ Wlin, const float* __restrict__ blin,
    float* __restrict__ Out, int N) {
  __shared__ unsigned short smem[32768];  // 64KB: phase1 staging, phase2 h3
  int t = threadIdx.x;
  int lane = t & 63;
  int w = t >> 6;
  int wr = (w >> 1) * 64, wc = (w & 1) * 64;
  int block_row = blockIdx.x * 128;

  int kg = lane & 3;
  int rr = lane >> 2;
  int fr = lane & 15;
  int fkb = (lane >> 4) * 16;
  int ke = (lane >> 4) * 8;  // k element offset within 32-elem K-slab
  int colw = lane & 15;

  // preload Wlin B-fragments (4 K-slabs x 8 elems), split hi/lo
  bf16x8 wbh[4], wbl[4];
#pragma unroll
  for (int ks = 0; ks < 4; ++ks) {
#pragma unroll
    for (int e = 0; e < 8; ++e) {
      float wv = Wlin[(size_t)(ks * 32 + ke + e) * 16 + colw];
      unsigned short h = f32_to_bf16(wv);
      wbh[ks][e] = (short)h;
      wbl[ks][e] = (short)f32_to_bf16(wv - bf16_to_f32(h));
    }
  }

  f32x4 acc[4][4];
#pragma unroll
  for (int m = 0; m < 4; ++m)
#pragma unroll
    for (int n = 0; n < 4; ++n) acc[m][n] = f32x4{0.f, 0.f, 0.f, 0.f};

  // phase-1 LDS carve: [sAhi[2] | sAlo[2] | sBhi[2] | sBlo[2]], 4096 shorts each
  auto sAhi = [&](int b) { return smem + b * 4096; };
  auto sAlo = [&](int b) { return smem + 8192 + b * 4096; };
  auto sBhi = [&](int b) { return smem + 16384 + b * 4096; };
  auto sBlo = [&](int b) { return smem + 24576 + b * 4096; };

  auto stage = [&](int kt, int b) {
    const unsigned short* gsrc;
    unsigned short* lbase;
    int isA = (w < 2);
    if (w == 0) { gsrc = (kt < 4) ? A1hi : A2hi; lbase = sAhi(b); }
    else if (w == 1) { gsrc = (kt < 4) ? A1lo : A2lo; lbase = sAlo(b); }
    else if (w == 2) { gsrc = Whi; lbase = sBhi(b); }
    else { gsrc = Wlo; lbase = sBlo(b); }
#pragma unroll
    for (int c = 0; c < 8; ++c) {
      int idx = c * 16 + rr;
      const char* src;
      if (isA) {
        int rg = block_row + idx;
        if (rg > N - 1) rg = N - 1;
        src = (const char*)gsrc + (size_t)rg * 256 + (kt & 3) * 64 + kg * 16;
      } else {
        src = (const char*)gsrc + (size_t)idx * 512 + kt * 64 + kg * 16;
      }
      gload_lds16(src, (char*)lbase + c * 1024);
    }
  };

  stage(0, 0);
  __syncthreads();

  for (int kt = 0; kt < 8; ++kt) {
    int cur = kt & 1;
    if (kt < 7) stage(kt + 1, cur ^ 1);
    bf16x8 a_hi[4], a_lo[4], b_hi[4], b_lo[4];
#pragma unroll
    for (int m = 0; m < 4; ++m) {
      int row = wr + m * 16 + fr;
      a_hi[m] = *reinterpret_cast<const bf16x8*>((const char*)sAhi(cur) + row * 64 + fkb);
      a_lo[m] = *reinterpret_cast<const bf16x8*>((const char*)sAlo(cur) + row * 64 + fkb);
    }
#pragma unroll
    for (int n = 0; n < 4; ++n) {
      int col = wc + n * 16 + fr;
      b_hi[n] = *reinterpret_cast<const bf16x8*>((const char*)sBhi(cur) + col * 64 + fkb);
      b_lo[n] = *reinterpret_cast<const bf16x8*>((const char*)sBlo(cur) + col * 64 + fkb);
    }
#pragma unroll
    for (int m = 0; m < 4; ++m)
#pragma unroll
      for (int n = 0; n < 4; ++n) {
        acc[m][n] = __builtin_amdgcn_mfma_f32_16x16x32_bf16(a_hi[m], b_hi[n], acc[m][n], 0, 0, 0);
        acc[m][n] = __builtin_amdgcn_mfma_f32_16x16x32_bf16(a_hi[m], b_lo[n], acc[m][n], 0, 0, 0);
        acc[m][n] = __builtin_amdgcn_mfma_f32_16x16x32_bf16(a_lo[m], b_hi[n], acc[m][n], 0, 0, 0);
      }
    __syncthreads();
  }

  // phase 2: h3 tile (bias+relu) -> LDS hi/lo (staging buffers are dead)
  unsigned short* hhi = smem;          // 128x128 bf16 hi (32KB)
  unsigned short* hlo = smem + 16384;  // 128x128 bf16 lo (32KB)
  float bv[4];
#pragma unroll
  for (int n = 0; n < 4; ++n) bv[n] = bias[wc + n * 16 + (lane & 15)];
#pragma unroll
  for (int m = 0; m < 4; ++m) {
#pragma unroll
    for (int n = 0; n < 4; ++n) {
#pragma unroll
      for (int j = 0; j < 4; ++j) {
        int row_l = wr + m * 16 + (lane >> 4) * 4 + j;
        int col = wc + n * 16 + (lane & 15);
        float v = fmaxf(acc[m][n][j] + bv[n], 0.f);
        unsigned short h = f32_to_bf16(v);
        hhi[row_l * 128 + col] = h;
        hlo[row_l * 128 + col] = f32_to_bf16(v - bf16_to_f32(h));
      }
    }
  }
  __syncthreads();

  // mini-GEMM: out[128][16] = h3 @ Wlin + blin; wave w owns m-tiles {2w, 2w+1}
  float bo = blin[colw];
#pragma unroll
  for (int m2 = 0; m2 < 2; ++m2) {
    int mtile = w * 2 + m2;
    f32x4 a2 = f32x4{0.f, 0.f, 0.f, 0.f};
#pragma unroll
    for (int ks = 0; ks < 4; ++ks) {
      int row = mtile * 16 + fr;
      bf16x8 ah = *reinterpret_cast<const bf16x8*>(hhi + row * 128 + ks * 32 + ke);
      bf16x8 al = *reinterpret_cast<const bf16x8*>(hlo + row * 128 + ks * 32 + ke);
      a2 = __builtin_amdgcn_mfma_f32_16x16x32_bf16(ah, wbh[ks], a2, 0, 0, 0);
      a2 = __builtin_amdgcn_mfma_f32_16x16x32_bf16(ah, wbl[ks], a2, 0, 0, 0);
      a2 = __builtin_amdgcn_mfma_f32_16x16x32_bf16(al, wbh[ks], a2, 0, 0, 0);
    }
#pragma unroll
    for (int j = 0; j < 4; ++j) {
      int row = mtile * 16 + (lane >> 4) * 4 + j;
      int g = block_row + row;
      if (g < N) Out[(size_t)g * 16 + colw] = a2[j] + bo;
    }
  }
}

extern "C" void kernel_launch(void* const* d_in, const int* in_sizes, int n_in,
                              void* d_out, int out_size, void* d_ws, size_t ws_size,
                              hipStream_t stream) {
  if (n_in < 13) return;
  const float* x = (const float*)d_in[0];
  const int* ei = (const int*)d_in[1];
  const float* W1l = (const float*)d_in[2];
  const float* b1 = (const float*)d_in[3];
  const float* W1r = (const float*)d_in[4];
  const float* W2l = (const float*)d_in[5];
  const float* b2 = (const float*)d_in[6];
  const float* W2r = (const float*)d_in[7];
  const float* W3l = (const float*)d_in[8];
  const float* b3 = (const float*)d_in[9];
  const float* W3r = (const float*)d_in[10];
  const float* Wlin = (const float*)d_in[11];
  const float* blin = (const float*)d_in[12];
  float* out = (float*)d_out;

  const int N = in_sizes[0] / 128;
  const int E = in_sizes[1] / 2;

  char* w = (char*)d_ws;
  size_t off = 0;
  auto alloc = [&](size_t bytes) -> void* {
    off = (off + 255) & ~(size_t)255;
    void* p = (void*)(w + off);
    off += bytes;
    return p;
  };
  size_t actB = (size_t)N * 128 * 2;
  unsigned short* Xhi = (unsigned short*)alloc(actB);
  unsigned short* Xlo = (unsigned short*)alloc(actB);
  unsigned short* Ahi = (unsigned short*)alloc(actB);
  unsigned short* Alo = (unsigned short*)alloc(actB);
  unsigned short* Mhi = (unsigned short*)alloc(actB);
  unsigned short* Mlo = (unsigned short*)alloc(actB);
  unsigned short* Wt[6];
  for (int i = 0; i < 6; ++i) Wt[i] = (unsigned short*)alloc(128 * 256 * 2);
  int* deg = (int*)alloc((size_t)N * 4);
  int* row_ptr = (int*)alloc((size_t)(N + 1) * 4);
  int* col_idx = (int*)alloc((size_t)E * 4);
  int* erank = (int*)alloc((size_t)E * 4);
  float* invdeg = (float*)alloc((size_t)N * 4);
  int* flag = (int*)alloc(4);
  int* bsum = (int*)alloc((size_t)1024 * 4);
  (void)ws_size;

  const int nbScan = (N + 1023) / 1024;

  // CSR build + operand prep
  k_zero_i32<<<(N + 255) / 256, 256, 0, stream>>>(deg, N);
  k_detect<<<1, 256, 0, stream>>>(ei, flag);
  k_count<<<(E + 255) / 256, 256, 0, stream>>>(ei, flag, deg, erank, E);
  k_split<<<(N * 32 + 255) / 256, 256, 0, stream>>>(x, Xhi, Xlo, N * 32);
  k_prep_w3<<<384, 256, 0, stream>>>(W1l, W1r, W2l, W2r, W3l, W3r,
                                     Wt[0], Wt[1], Wt[2], Wt[3], Wt[4], Wt[5]);
  k_scan1<<<nbScan, 256, 0, stream>>>(deg, bsum, N);
  k_scan2<<<1, 1024, 0, stream>>>(bsum, row_ptr, nbScan, N);
  k_scan3<<<nbScan, 256, 0, stream>>>(deg, bsum, row_ptr, invdeg, N);
  k_fill<<<(E + 255) / 256, 256, 0, stream>>>(ei, flag, row_ptr, erank, col_idx, E);

  int aggBlocks = (N * 64 + 255) / 256;
  int gemmBlocks = (N + 127) / 128;

  // layer 1: X -> A (h1)
  k_aggregate<<<aggBlocks, 256, 0, stream>>>(Xhi, row_ptr, col_idx, invdeg,
                                             (unsigned int*)Mhi, (unsigned int*)Mlo, N);
  k_mfma_gemm<<<gemmBlocks, 256, 0, stream>>>(Mhi, Mlo, Xhi, Xlo, Wt[0], Wt[1], b1,
                                              Ahi, Alo, N);
  // layer 2: A -> X (h2)
  k_aggregate<<<aggBlocks, 256, 0, stream>>>(Ahi, row_ptr, col_idx, invdeg,
                                             (unsigned int*)Mhi, (unsigned int*)Mlo, N);
  k_mfma_gemm<<<gemmBlocks, 256, 0, stream>>>(Mhi, Mlo, Ahi, Alo, Wt[2], Wt[3], b2,
                                              Xhi, Xlo, N);
  // layer 3 + final linear fused: X -> out
  k_aggregate<<<aggBlocks, 256, 0, stream>>>(Xhi, row_ptr, col_idx, invdeg,
                                             (unsigned int*)Mhi, (unsigned int*)Mlo, N);
  k_mfma_gemm_final<<<gemmBlocks, 256, 0, stream>>>(Mhi, Mlo, Xhi, Xlo, Wt[4], Wt[5],
                                                    b3, Wlin, blin, out, N);
}